// Round 1
// 1022.404 us; speedup vs baseline: 1.4345x; 1.4345x over previous
//
#include <hip/hip_runtime.h>
#include <hip/hip_bf16.h>
#include <math.h>

typedef __bf16 bf16;
typedef __attribute__((ext_vector_type(8))) __bf16 bf16x8;
typedef __attribute__((ext_vector_type(4))) __bf16 bf16x4;
typedef __attribute__((ext_vector_type(4))) float f32x4;

#define B_N 131072
#define D_N 512
#define S_N 64
#define H_N 128
#define KU 576  // folded K for GEMM4': 512 (x) + 64 (sw @ (ref@wu_bot))

#define MFMA(a, b, c) __builtin_amdgcn_mfma_f32_16x16x32_bf16((a), (b), (c), 0, 0, 0)

// Fragment load from row-major bf16 [*, ld]. A-op: row = M row; B-op from B^T
// stored [N][K]: row = N row. lane m/n = lane&15, k = k0 + (lane>>4)*8.
__device__ __forceinline__ bf16x8 ldfrag(const bf16* __restrict__ base, int ld,
                                         int row, int k0, int lane) {
  return *(const bf16x8*)(base + (size_t)(row + (lane & 15)) * ld + k0 + ((lane >> 4) << 3));
}

// Same fragment, but source is row-major FP32: two float4 loads + cvt to bf16.
__device__ __forceinline__ bf16x8 ldfrag_f32(const float* __restrict__ base, int ld,
                                             int row, int k0, int lane) {
  const float* p = base + (size_t)(row + (lane & 15)) * ld + k0 + ((lane >> 4) << 3);
  float4 a = *(const float4*)p;
  float4 b = *(const float4*)(p + 4);
  bf16x8 r;
  r[0] = (bf16)a.x; r[1] = (bf16)a.y; r[2] = (bf16)a.z; r[3] = (bf16)a.w;
  r[4] = (bf16)b.x; r[5] = (bf16)b.y; r[6] = (bf16)b.z; r[7] = (bf16)b.w;
  return r;
}

// ---- pack: fp32 [R][C] -> transposed bf16 [C][R] with dst leading dim ldd ----
__global__ void ktr2(const float* __restrict__ src, bf16* __restrict__ dst,
                     int R, int C, int ldd) {
  int i = blockIdx.x * 256 + threadIdx.x;
  if (i < R * C) {
    int r = i / C, c = i - r * C;
    dst[(size_t)c * ldd + r] = (bf16)src[i];
  }
}

// ---- kM: wuM[n][512+s] = sum_d ref[s][d] * wu[512+d][n]  (f32 accumulate) ----
// This folds sel @ wu_bot into sw @ M, shrinking GEMM4's K from 1024 to 576.
__global__ void kM(const float* __restrict__ ref, const float* __restrict__ wu,
                   bf16* __restrict__ wuM) {
  int idx = blockIdx.x * 256 + threadIdx.x;  // 64*512 = 32768 outputs
  int s = idx >> 9, n = idx & 511;
  const float* rp = ref + (size_t)s * D_N;
  const float* wp = wu + (size_t)512 * D_N + n;  // wu_bot column n
  float acc = 0.f;
#pragma unroll 8
  for (int d = 0; d < 512; d++) acc += rp[d] * wp[(size_t)d * D_N];
  wuM[(size_t)n * KU + 512 + s] = (bf16)acc;
}

// ---------------- fused kernel: k1 + k2 in one pass over the batch ----------
// Per block: 128 batch rows, 4 waves x 32 rows. Stages:
//   S1 h=relu(x@w1+b1) -> S2 logits=h@w2+b2 -> softmax (sw in LDS, 2 layouts)
//   -> S3 sel=sw@ref (write out) -> G4' upd=tanh(x@wu_top + sw@M + bu)
//   -> G5 accum += sw^T @ upd (atomics)
// sw never touches HBM; sel is written once, never re-read; x read once per
// stage (GEMM1 + 2 N-chunks of GEMM4').
__global__ __launch_bounds__(256, 2) void kfused(
    const float* __restrict__ x, const bf16* __restrict__ w1T, const float* __restrict__ b1,
    const bf16* __restrict__ w2T, const float* __restrict__ b2,
    const bf16* __restrict__ refT, const bf16* __restrict__ wuM, const float* __restrict__ bu,
    float* __restrict__ sel_out, float* __restrict__ accum) {
  __shared__ bf16 hbuf[128 * 136];   // S1/S2: h[batch][h]; later aliased as updT[d][batch]
  __shared__ bf16 swbuf[128 * 72];   // [batch][state] (wave-private rows)
  __shared__ bf16 swT[64 * 136];     // [state][batch] (block-shared, read-only after barrier)

  const int tid = threadIdx.x;
  const int wave = tid >> 6, lane = tid & 63;
  const int col = lane & 15, quad = lane >> 4;
  const int row0 = blockIdx.x * 128;
  const int bbase = wave * 32;  // this wave's 32 batch rows within the tile

  // ---- Stage 1: hT = w1T @ x^T   (M=h 128, N=batch 32/wave, K=512)
  f32x4 acc1[8][2];
#pragma unroll
  for (int mt = 0; mt < 8; mt++)
#pragma unroll
    for (int nt = 0; nt < 2; nt++) acc1[mt][nt] = (f32x4){0.f, 0.f, 0.f, 0.f};

  for (int k0 = 0; k0 < 512; k0 += 32) {
    bf16x8 bfr[2];
#pragma unroll
    for (int nt = 0; nt < 2; nt++)
      bfr[nt] = ldfrag_f32(x, D_N, row0 + bbase + nt * 16, k0, lane);
#pragma unroll
    for (int mt = 0; mt < 8; mt++) {
      bf16x8 afr = ldfrag(w1T, D_N, mt * 16, k0, lane);
      acc1[mt][0] = MFMA(afr, bfr[0], acc1[mt][0]);
      acc1[mt][1] = MFMA(afr, bfr[1], acc1[mt][1]);
    }
  }
  // bias + relu, store h row-major [batch][h]
#pragma unroll
  for (int nt = 0; nt < 2; nt++) {
    int batch = bbase + nt * 16 + col;
#pragma unroll
    for (int mt = 0; mt < 8; mt++) {
      int h0 = mt * 16 + quad * 4;
      bf16x4 pk;
#pragma unroll
      for (int r = 0; r < 4; r++) {
        float v = acc1[mt][nt][r] + b1[h0 + r];
        pk[r] = (bf16)fmaxf(v, 0.f);
      }
      *(bf16x4*)&hbuf[batch * 136 + h0] = pk;
    }
  }
  // (no barrier: hbuf/swbuf rows are wave-private here)

  // ---- Stage 2: logitsT = w2T @ h^T  (M=state 64, N=batch 32/wave, K=128)
  f32x4 acc2[4][2];
#pragma unroll
  for (int mt = 0; mt < 4; mt++)
#pragma unroll
    for (int nt = 0; nt < 2; nt++) acc2[mt][nt] = (f32x4){0.f, 0.f, 0.f, 0.f};

  for (int k0 = 0; k0 < 128; k0 += 32) {
    bf16x8 bfr[2];
#pragma unroll
    for (int nt = 0; nt < 2; nt++) {
      int batch = bbase + nt * 16 + col;
      bfr[nt] = *(const bf16x8*)&hbuf[batch * 136 + k0 + quad * 8];
    }
#pragma unroll
    for (int mt = 0; mt < 4; mt++) {
      bf16x8 afr = ldfrag(w2T, H_N, mt * 16, k0, lane);
      acc2[mt][0] = MFMA(afr, bfr[0], acc2[mt][0]);
      acc2[mt][1] = MFMA(afr, bfr[1], acc2[mt][1]);
    }
  }

  // ---- softmax over 64 states per batch column (quads hold disjoint states)
#pragma unroll
  for (int nt = 0; nt < 2; nt++) {
    int batch = bbase + nt * 16 + col;
    float v[16];
#pragma unroll
    for (int mt = 0; mt < 4; mt++)
#pragma unroll
      for (int r = 0; r < 4; r++)
        v[mt * 4 + r] = acc2[mt][nt][r] + b2[mt * 16 + quad * 4 + r];
    float mx = v[0];
#pragma unroll
    for (int i = 1; i < 16; i++) mx = fmaxf(mx, v[i]);
    mx = fmaxf(mx, __shfl_xor(mx, 16));
    mx = fmaxf(mx, __shfl_xor(mx, 32));
    float s = 0.f;
#pragma unroll
    for (int i = 0; i < 16; i++) {
      v[i] = __expf(v[i] - mx);
      s += v[i];
    }
    s += __shfl_xor(s, 16);
    s += __shfl_xor(s, 32);
    float inv = 1.f / s;
#pragma unroll
    for (int mt = 0; mt < 4; mt++) {
      int s0 = mt * 16 + quad * 4;
      bf16x4 pk;
#pragma unroll
      for (int r = 0; r < 4; r++) pk[r] = (bf16)(v[mt * 4 + r] * inv);
      *(bf16x4*)&swbuf[batch * 72 + s0] = pk;
#pragma unroll
      for (int r = 0; r < 4; r++) swT[(s0 + r) * 136 + batch] = pk[r];  // transposed copy (LDS only)
    }
  }

  // ---- Stage 3: sel = sw @ ref  (M=batch 32/wave, N=512 in 4 chunks, K=64)
  for (int c = 0; c < 4; c++) {
    int d0 = c * 128;
    f32x4 acc3[2][8];
#pragma unroll
    for (int mt = 0; mt < 2; mt++)
#pragma unroll
      for (int nt = 0; nt < 8; nt++) acc3[mt][nt] = (f32x4){0.f, 0.f, 0.f, 0.f};
#pragma unroll
    for (int k0 = 0; k0 < 64; k0 += 32) {
      bf16x8 afr[2];
#pragma unroll
      for (int mt = 0; mt < 2; mt++) {
        int batch = bbase + mt * 16 + col;
        afr[mt] = *(const bf16x8*)&swbuf[batch * 72 + k0 + quad * 8];
      }
#pragma unroll
      for (int nt = 0; nt < 8; nt++) {
        bf16x8 bfr = ldfrag(refT, S_N, d0 + nt * 16, k0, lane);
        acc3[0][nt] = MFMA(afr[0], bfr, acc3[0][nt]);
        acc3[1][nt] = MFMA(afr[1], bfr, acc3[1][nt]);
      }
    }
#pragma unroll
    for (int nt = 0; nt < 8; nt++) {
#pragma unroll
      for (int mt = 0; mt < 2; mt++) {
        int brow = row0 + bbase + mt * 16 + quad * 4;
        int d = d0 + nt * 16 + col;
#pragma unroll
        for (int r = 0; r < 4; r++)
          sel_out[(size_t)(brow + r) * D_N + d] = acc3[mt][nt][r];
      }
    }
  }

  __syncthreads();  // swT complete; hbuf free for reuse as updT

  // hoist GEMM5 A fragments (invariant across chunks): sw^T[state][batch 0..127]
  bf16x8 swfrag[4];
#pragma unroll
  for (int kk = 0; kk < 4; kk++)
    swfrag[kk] = *(const bf16x8*)&swT[(wave * 16 + col) * 136 + kk * 32 + quad * 8];

  bf16* updT = hbuf;  // [d_local 128][batch 136]

  // ---- GEMM4': upd = tanh(x @ wu_top + sw @ M + bu), N in 2 chunks of 256
  for (int c = 0; c < 2; c++) {
    const int d0 = c * 256;
    f32x4 acc4[2][16];
#pragma unroll
    for (int mt = 0; mt < 2; mt++)
#pragma unroll
      for (int nt = 0; nt < 16; nt++) acc4[mt][nt] = (f32x4){0.f, 0.f, 0.f, 0.f};

    for (int k0 = 0; k0 < 512; k0 += 32) {  // x part of K
      bf16x8 afr[2];
#pragma unroll
      for (int mt = 0; mt < 2; mt++)
        afr[mt] = ldfrag_f32(x, D_N, row0 + bbase + mt * 16, k0, lane);
#pragma unroll
      for (int nt = 0; nt < 16; nt++) {
        bf16x8 bfr = ldfrag(wuM, KU, d0 + nt * 16, k0, lane);
        acc4[0][nt] = MFMA(afr[0], bfr, acc4[0][nt]);
        acc4[1][nt] = MFMA(afr[1], bfr, acc4[1][nt]);
      }
    }
#pragma unroll
    for (int k0 = 512; k0 < 576; k0 += 32) {  // folded sw @ M part of K
      bf16x8 afr[2];
#pragma unroll
      for (int mt = 0; mt < 2; mt++) {
        int batch = bbase + mt * 16 + col;
        afr[mt] = *(const bf16x8*)&swbuf[batch * 72 + (k0 - 512) + quad * 8];
      }
#pragma unroll
      for (int nt = 0; nt < 16; nt++) {
        bf16x8 bfr = ldfrag(wuM, KU, d0 + nt * 16, k0, lane);
        acc4[0][nt] = MFMA(afr[0], bfr, acc4[0][nt]);
        acc4[1][nt] = MFMA(afr[1], bfr, acc4[1][nt]);
      }
    }

    // tanh + GEMM5 in two 128-d halves (updT LDS region holds 128 d at a time)
#pragma unroll
    for (int h = 0; h < 2; h++) {
      if (c | h) __syncthreads();  // previous half's GEMM5 reads of updT done
#pragma unroll
      for (int nn = 0; nn < 8; nn++) {
        int dl = nn * 16 + col;
        float bv = bu[d0 + h * 128 + dl];
#pragma unroll
        for (int mt = 0; mt < 2; mt++) {
          int b0 = bbase + mt * 16 + quad * 4;
          bf16x4 pk;
#pragma unroll
          for (int r = 0; r < 4; r++) {
            float v = acc4[mt][h * 8 + nn][r] + bv;
            // tanh(v) = 1 - 2/(e^{2v}+1); overflow-safe (e=inf -> 1, e=0 -> -1)
            float e = __expf(2.f * v);
            pk[r] = (bf16)(1.f - 2.f / (e + 1.f));
          }
          *(bf16x4*)&updT[dl * 136 + b0] = pk;
        }
      }
      __syncthreads();

      // GEMM5: partial[s][d] += sw^T[s][i] * updT[d][i]  (M=16/wave, N=128, K=128)
      f32x4 acc5[8];
#pragma unroll
      for (int nn = 0; nn < 8; nn++) acc5[nn] = (f32x4){0.f, 0.f, 0.f, 0.f};
#pragma unroll
      for (int kk = 0; kk < 4; kk++) {
#pragma unroll
        for (int nn = 0; nn < 8; nn++) {
          bf16x8 bfr = *(const bf16x8*)&updT[(nn * 16 + col) * 136 + kk * 32 + quad * 8];
          acc5[nn] = MFMA(swfrag[kk], bfr, acc5[nn]);
        }
      }
#pragma unroll
      for (int nn = 0; nn < 8; nn++) {
#pragma unroll
        for (int r = 0; r < 4; r++) {
          int st = wave * 16 + quad * 4 + r;
          int d = d0 + h * 128 + nn * 16 + col;
          atomicAdd(&accum[st * D_N + d], acc5[nn][r]);
        }
      }
    }
  }
}

// ---------------- kernel 3: new_ref = ref + LR * accum ----------------
__global__ void k3(const float* __restrict__ ref, const float* __restrict__ accum,
                   float* __restrict__ out2) {
  int i = blockIdx.x * 256 + threadIdx.x;  // 32768 total
  out2[i] = ref[i] + 0.01f * accum[i];
}

extern "C" void kernel_launch(void* const* d_in, const int* in_sizes, int n_in,
                              void* d_out, int out_size, void* d_ws, size_t ws_size,
                              hipStream_t stream) {
  const float* x   = (const float*)d_in[0];
  const float* ref = (const float*)d_in[1];
  const float* w1  = (const float*)d_in[2];
  const float* b1  = (const float*)d_in[3];
  const float* w2  = (const float*)d_in[4];
  const float* b2  = (const float*)d_in[5];
  const float* wu  = (const float*)d_in[6];
  const float* bu  = (const float*)d_in[7];
  float* out_sel = (float*)d_out;
  float* out_ref = out_sel + (size_t)B_N * D_N;

  char* ws = (char*)d_ws;
  float* accum = (float*)(ws);             // 64*512*4    = 131072 B
  bf16*  w1T   = (bf16*)(ws + 131072);     // 128*512*2   = 131072 B
  bf16*  w2T   = (bf16*)(ws + 262144);     // 64*128*2    = 16384 B
  bf16*  refT  = (bf16*)(ws + 278528);     // 512*64*2    = 65536 B
  bf16*  wuM   = (bf16*)(ws + 344064);     // 512*576*2   = 589824 B

  hipMemsetAsync(accum, 0, S_N * D_N * sizeof(float), stream);
  ktr2<<<(512 * 128 + 255) / 256, 256, 0, stream>>>(w1, w1T, 512, 128, 512);
  ktr2<<<(128 * 64 + 255) / 256, 256, 0, stream>>>(w2, w2T, 128, 64, 128);
  ktr2<<<(64 * 512 + 255) / 256, 256, 0, stream>>>(ref, refT, 64, 512, 64);
  ktr2<<<(512 * 512 + 255) / 256, 256, 0, stream>>>(wu, wuM, 512, 512, KU);  // wu_top^T
  kM<<<128, 256, 0, stream>>>(ref, wu, wuM);                                 // (ref@wu_bot)^T

  kfused<<<B_N / 128, 256, 0, stream>>>(x, w1T, b1, w2T, b2, refT, wuM, bu, out_sel, accum);
  k3<<<S_N * D_N / 256, 256, 0, stream>>>(ref, accum, out_ref);
}